// Round 9
// baseline (524.494 us; speedup 1.0000x reference)
//
#include <hip/hip_runtime.h>

#define BATCH 65536

typedef float f32x4 __attribute__((ext_vector_type(4)));
typedef _Float16 f16x8 __attribute__((ext_vector_type(8)));

__device__ __forceinline__ void async_ld16(const void* g, void* l) {
  __builtin_amdgcn_global_load_lds(
      (const __attribute__((address_space(1))) void*)g,
      (__attribute__((address_space(3))) void*)l, 16, 0, 0);
}

__device__ __forceinline__ float act_f(float x, float a0, float a1, float a2,
                                       float a3, float a4) {
  float ax = fabsf(x);
  float e = __builtin_amdgcn_exp2f(ax * -2.8853900817779268f);
  float th = (1.0f - e) * __builtin_amdgcn_rcpf(1.0f + e);
  th = copysignf(th, x);
  float arg = fmaf(a1, x, a2);
  float rev = arg * 0.15915494309189535f;
  rev -= floorf(rev);
  float s = __builtin_amdgcn_sinf(rev);
  return fmaf(a3, x, fmaf(a0 * th, s, a4));
}

// split + transpose weights: W[K][N] fp32 -> Wt_hi/lo[N][K] fp16
__global__ __launch_bounds__(256) void splitT_k(const float* __restrict__ W,
                                                _Float16* __restrict__ hi,
                                                _Float16* __restrict__ lo,
                                                int K, int N) {
  const int i = blockIdx.x * 256 + threadIdx.x;
  if (i >= K * N) return;
  const int k = i / N, n = i % N;
  const float w = W[i];
  const _Float16 h = (_Float16)w;
  hi[(size_t)n * K + k] = h;
  lo[(size_t)n * K + k] = (_Float16)(w - (float)h);
}

// pack bias + a^T into Pt[6][N]
__global__ __launch_bounds__(256) void prep_params(const float* __restrict__ b,
                                                   const float* __restrict__ a,
                                                   float* __restrict__ Pt,
                                                   int N) {
  const int c = blockIdx.x * 256 + threadIdx.x;
  if (c >= N) return;
  Pt[c] = b[c];
#pragma unroll
  for (int j = 0; j < 5; ++j) Pt[(1 + j) * N + c] = a[c * 5 + j];
}

// 3-product compensation, SWAPPED operands: first = weight frag (A-op),
// second = activation frag (B-op) -> D = C^T layout: lane holds
// row = m16, cols = quad*4 + r (consecutive).
__device__ __forceinline__ f32x4 mfma3s(f16x8 wh, f16x8 wl, f16x8 xh,
                                        f16x8 xl, f32x4 c) {
  c = __builtin_amdgcn_mfma_f32_16x16x32_f16(wh, xh, c, 0, 0, 0);
  c = __builtin_amdgcn_mfma_f32_16x16x32_f16(wh, xl, c, 0, 0, 0);
  c = __builtin_amdgcn_mfma_f32_16x16x32_f16(wl, xh, c, 0, 0, 0);
  return c;
}

// C = act(A @ Wt + b). Block 64 rows x 256 cols, BK=32, 4 waves side-by-side
// (wave = 64x64, MT=4 x NT=4; A-fragments wave-shared -> LDS broadcast).
// A: fp32 [M][K] (single plane, or DUALA: two half-K planes of row-stride
// 256), LDS-staged with 16B granule-XOR swizzle, hi/lo split in-register.
// B: Wt[N][K] fp16 hi/lo planes (L2-hot), LDS-staged, 16B-XOR swizzled.
// Epilogue !FINAL: direct f32x4 stores (C^T acc: [row=m16][4 consecutive
// cols]) -> contiguous full-line fp32 writes, no RMW. SPLITC: cols 0-255 of
// this x-tile go to C0/C1 chosen by blockIdx.x, row stride 256.
// Epilogue FINAL: act + fused softmax over N=256, f32x4 stores to Cout.
template <bool DUALA, bool SPLITC, bool FINAL, int NW>
__global__ __launch_bounds__(256, NW) void gemm_act(
    const float* __restrict__ Af0, const float* __restrict__ Af1,
    const _Float16* __restrict__ Bhi, const _Float16* __restrict__ Blo,
    const float* __restrict__ Pt, float* __restrict__ C0,
    float* __restrict__ C1, float* __restrict__ Cout, int K, int N) {
  __shared__ __align__(16) _Float16 smem[20480];  // 40 KB
  _Float16* sA = smem;                            // 8 KB (fp32 64x32)
  _Float16* sB = smem + 4096;                     // 32 KB (2 planes 256x32)

  const int tid = threadIdx.x;
  const int wv = tid >> 6, lane = tid & 63;
  const int m16 = lane & 15, quad = lane >> 4;
  const int col0 = blockIdx.x * 256;  // x = N-tiles (<=2, r4-proven locality)
  const int row0 = blockIdx.y * 64;
  const int rl4 = lane >> 2, sg4 = (lane & 3) ^ ((rl4 >> 1) & 3);  // 64B rows
  const int rl8 = lane >> 3, sg8 = (lane & 7) ^ rl8;               // 128B rows
  const int fswz = (quad ^ ((m16 >> 1) & 3)) * 8;
  const int rc7 = m16 & 7;

  f32x4 acc[4][4];
  const f32x4 zero = {0.f, 0.f, 0.f, 0.f};
#pragma unroll
  for (int i = 0; i < 4; ++i)
#pragma unroll
    for (int j = 0; j < 4; ++j) acc[i][j] = zero;

  const int nk = K >> 5;
  for (int kt = 0; kt < nk; ++kt) {
    const int k0 = kt << 5;
    // ---- stage A: fp32 64 rows x 32 k, 8 chunks of 8 rows ----
    {
      const float* Ab;
      int koff, AK;
      if constexpr (DUALA) {
        Ab = (k0 < 256) ? Af0 : Af1;
        koff = k0 & 255;
        AK = 256;
      } else {
        Ab = Af0;
        koff = k0;
        AK = K;
      }
      float* sAf = (float*)sA;
#pragma unroll
      for (int t = 0; t < 2; ++t) {
        const int c = wv * 2 + t;
        const size_t ga = (size_t)(row0 + c * 8 + rl8) * AK + koff + sg8 * 4;
        async_ld16(Ab + ga, (void*)&sAf[c * 256]);
      }
    }
    // ---- stage B: 256 cols x 32 k, 2 planes ----
#pragma unroll
    for (int t = 0; t < 4; ++t) {
      const int c = wv * 4 + t;
      const size_t gb = (size_t)(col0 + c * 16 + rl4) * K + k0 + sg4 * 8;
      async_ld16(Bhi + gb, (void*)&sB[c * 512]);
      async_ld16(Blo + gb, (void*)&sB[8192 + c * 512]);
    }
    __syncthreads();

    // ---- A fragments: fp32 read + in-register hi/lo split (broadcast) ----
    f16x8 ah[4], al[4];
#pragma unroll
    for (int tm = 0; tm < 4; ++tm) {
      const int arow = tm * 16 + m16;
      const float* sAf = (const float*)sA + arow * 32;
      const f32x4 x0 = *(const f32x4*)(sAf + ((2 * quad) ^ rc7) * 4);
      const f32x4 x1 = *(const f32x4*)(sAf + ((2 * quad + 1) ^ rc7) * 4);
#pragma unroll
      for (int j = 0; j < 4; ++j) {
        const _Float16 h0 = (_Float16)x0[j];
        ah[tm][j] = h0;
        al[tm][j] = (_Float16)(x0[j] - (float)h0);
        const _Float16 h1 = (_Float16)x1[j];
        ah[tm][4 + j] = h1;
        al[tm][4 + j] = (_Float16)(x1[j] - (float)h1);
      }
    }
    // ---- B fragments + MFMA ----
#pragma unroll
    for (int tn = 0; tn < 4; ++tn) {
      const int bcol = wv * 64 + tn * 16 + m16;
      const int idx = bcol * 32 + fswz;
      const f16x8 bh = *(const f16x8*)&sB[idx];
      const f16x8 bl = *(const f16x8*)&sB[8192 + idx];
#pragma unroll
      for (int tm = 0; tm < 4; ++tm)
        acc[tm][tn] = mfma3s(bh, bl, ah[tm], al[tm], acc[tm][tn]);
    }
    __syncthreads();
  }

  if constexpr (!FINAL) {
    // ---- epilogue: bias+act, direct f32x4 stores (contiguous per row) ----
    float* Cb = SPLITC ? (blockIdx.x ? C1 : C0) : C0;
    const int cstr = SPLITC ? 256 : N;
#pragma unroll
    for (int tn = 0; tn < 4; ++tn) {
      const int cb = wv * 64 + tn * 16 + quad * 4;  // local col in [0,256)
      const int gcol = col0 + cb;
      f32x4 P[6];
#pragma unroll
      for (int q = 0; q < 6; ++q) P[q] = *(const f32x4*)&Pt[q * N + gcol];
#pragma unroll
      for (int tm = 0; tm < 4; ++tm) {
        const int row = row0 + tm * 16 + m16;
        f32x4 y;
#pragma unroll
        for (int r = 0; r < 4; ++r)
          y[r] = act_f(acc[tm][tn][r] + P[0][r], P[1][r], P[2][r], P[3][r],
                       P[4][r], P[5][r]);
        *(f32x4*)&Cb[(size_t)row * cstr + (SPLITC ? cb : gcol)] = y;
      }
    }
  } else {
    // ---- epilogue: act + fused softmax over N=256 (4 waves x 64 cols) ----
    const float L2E = 1.4426950408889634f;
    float mx[4], sm[4];
#pragma unroll
    for (int tm = 0; tm < 4; ++tm) mx[tm] = -1e30f;
#pragma unroll
    for (int tn = 0; tn < 4; ++tn) {
      const int colb = wv * 64 + tn * 16 + quad * 4;
      f32x4 P[6];
#pragma unroll
      for (int q = 0; q < 6; ++q) P[q] = *(const f32x4*)&Pt[q * 256 + colb];
#pragma unroll
      for (int tm = 0; tm < 4; ++tm)
#pragma unroll
        for (int r = 0; r < 4; ++r) {
          const float y = act_f(acc[tm][tn][r] + P[0][r], P[1][r], P[2][r],
                                P[3][r], P[4][r], P[5][r]);
          acc[tm][tn][r] = y;
          mx[tm] = fmaxf(mx[tm], y);
        }
    }
#pragma unroll
    for (int tm = 0; tm < 4; ++tm) {
      mx[tm] = fmaxf(mx[tm], __shfl_xor(mx[tm], 16));
      mx[tm] = fmaxf(mx[tm], __shfl_xor(mx[tm], 32));
    }
    float* part = (float*)smem;
    if (quad == 0) {
#pragma unroll
      for (int tm = 0; tm < 4; ++tm) part[wv * 64 + tm * 16 + m16] = mx[tm];
    }
    __syncthreads();
#pragma unroll
    for (int tm = 0; tm < 4; ++tm) {
      const int rl = tm * 16 + m16;
      float M = part[rl];
#pragma unroll
      for (int w = 1; w < 4; ++w) M = fmaxf(M, part[w * 64 + rl]);
      mx[tm] = M;
      sm[tm] = 0.f;
    }
#pragma unroll
    for (int tn = 0; tn < 4; ++tn)
#pragma unroll
      for (int tm = 0; tm < 4; ++tm)
#pragma unroll
        for (int r = 0; r < 4; ++r) {
          const float e =
              __builtin_amdgcn_exp2f((acc[tm][tn][r] - mx[tm]) * L2E);
          acc[tm][tn][r] = e;
          sm[tm] += e;
        }
#pragma unroll
    for (int tm = 0; tm < 4; ++tm) {
      sm[tm] += __shfl_xor(sm[tm], 16);
      sm[tm] += __shfl_xor(sm[tm], 32);
    }
    __syncthreads();
    if (quad == 0) {
#pragma unroll
      for (int tm = 0; tm < 4; ++tm)
        part[256 + wv * 64 + tm * 16 + m16] = sm[tm];
    }
    __syncthreads();
    float sc[4];
#pragma unroll
    for (int tm = 0; tm < 4; ++tm) {
      const int rl = tm * 16 + m16;
      float S = part[256 + rl];
#pragma unroll
      for (int w = 1; w < 4; ++w) S += part[256 + w * 64 + rl];
      sc[tm] = __builtin_amdgcn_rcpf(S);
    }
#pragma unroll
    for (int tn = 0; tn < 4; ++tn) {
      const int colb = wv * 64 + tn * 16 + quad * 4;
#pragma unroll
      for (int tm = 0; tm < 4; ++tm) {
        const int row = row0 + tm * 16 + m16;
        f32x4 v = acc[tm][tn];
#pragma unroll
        for (int r = 0; r < 4; ++r) v[r] *= sc[tm];
        *(f32x4*)&Cout[(size_t)row * 256 + colb] = v;
      }
    }
  }
}

extern "C" void kernel_launch(void* const* d_in, const int* in_sizes, int n_in,
                              void* d_out, int out_size, void* d_ws,
                              size_t ws_size, hipStream_t stream) {
  const float* data = (const float*)d_in[0];
  const float* W1 = (const float*)d_in[1];
  const float* b1 = (const float*)d_in[2];
  const float* a1 = (const float*)d_in[3];
  const float* W2 = (const float*)d_in[4];
  const float* b2 = (const float*)d_in[5];
  const float* a2 = (const float*)d_in[6];
  const float* W3 = (const float*)d_in[7];
  const float* b3 = (const float*)d_in[8];
  const float* a3 = (const float*)d_in[9];
  float* out = (float*)d_out;

  char* ws = (char*)d_ws;
  const size_t KB = 1024, MB = 1024 * 1024;
  _Float16* w1hi = (_Float16*)(ws + 0 * KB);     // Wt1[512][256]
  _Float16* w1lo = (_Float16*)(ws + 256 * KB);
  _Float16* w2hi = (_Float16*)(ws + 512 * KB);   // Wt2[512][512]
  _Float16* w2lo = (_Float16*)(ws + 1024 * KB);
  _Float16* w3hi = (_Float16*)(ws + 1536 * KB);  // Wt3[256][512]
  _Float16* w3lo = (_Float16*)(ws + 1792 * KB);
  float* Pt1 = (float*)(ws + 2048 * KB);         // [6][512]
  float* Pt2 = (float*)(ws + 2064 * KB);         // [6][512]
  float* Pt3 = (float*)(ws + 2080 * KB);         // [6][256]
  // h1: fp32 [65536][512] = 128 MB. h2 fp32 split column-wise:
  //   cols 0-255  -> d_out (exactly 64 MB; GEMM3 reads only its own rows
  //                  before its epilogue overwrites them -> alias-safe)
  //   cols 256-511 -> ws (64 MB)
  float* h1 = (float*)(ws + 4 * MB);
  float* h2b = (float*)(ws + 4 * MB + 128 * MB);
  float* h2a = (float*)d_out;

  splitT_k<<<(256 * 512 + 255) / 256, 256, 0, stream>>>(W1, w1hi, w1lo, 256, 512);
  splitT_k<<<(512 * 512 + 255) / 256, 256, 0, stream>>>(W2, w2hi, w2lo, 512, 512);
  splitT_k<<<(512 * 256 + 255) / 256, 256, 0, stream>>>(W3, w3hi, w3lo, 512, 256);
  prep_params<<<2, 256, 0, stream>>>(b1, a1, Pt1, 512);
  prep_params<<<2, 256, 0, stream>>>(b2, a2, Pt2, 512);
  prep_params<<<1, 256, 0, stream>>>(b3, a3, Pt3, 256);

  // 64x256 blocks; grid x = N-tiles (2 strip-mates, r4-proven A-locality)
  gemm_act<false, false, false, 4><<<dim3(2, BATCH / 64), 256, 0, stream>>>(
      data, nullptr, w1hi, w1lo, Pt1, h1, nullptr, nullptr, 256, 512);
  gemm_act<false, true, false, 4><<<dim3(2, BATCH / 64), 256, 0, stream>>>(
      h1, nullptr, w2hi, w2lo, Pt2, h2a, h2b, nullptr, 512, 512);
  gemm_act<true, false, true, 3><<<dim3(1, BATCH / 64), 256, 0, stream>>>(
      h2a, h2b, w3hi, w3lo, Pt3, nullptr, nullptr, out, 512, 256);
}